// Round 1
// baseline (434.714 us; speedup 1.0000x reference)
//
#include <hip/hip_runtime.h>
#include <math.h>

#define H   1024
#define H2  2048
#define L   100
#define V   50257

// ws float offsets (all multiples of 4 -> 16B aligned for float4)
#define WS_ATT   0      // 100 floats: attn logits, then attn weights
#define WS_CTX   128    // 1024 floats: context
#define WS_X     1280   // 1024 floats: relu(combine)
#define WS_HNEW  2304   // 1024 floats: h_new (aligned mirror of d_out[V..V+H))
#define WS_C     3328   // 1 float: max + log(sumexp)

__device__ __forceinline__ float wave_reduce_sum(float v) {
#pragma unroll
    for (int off = 32; off > 0; off >>= 1) v += __shfl_down(v, off);
    return v;
}

// K1: attn_logits[l] = dot(concat(embedded,h0), attn_W[l]) + attn_b[l]
// grid L x 256
__global__ void k_attn_logits(const int* __restrict__ tok,
                              const float* __restrict__ hidden,
                              const float* __restrict__ emb,
                              const float* __restrict__ attn_W,
                              const float* __restrict__ attn_b,
                              float* __restrict__ ws) {
    const int l = blockIdx.x;
    const int t = threadIdx.x;  // 256
    const float* __restrict__ row = attn_W + (size_t)l * H2;
    const float* __restrict__ e   = emb + (size_t)tok[0] * H;
    float acc = 0.f;
#pragma unroll
    for (int base = 0; base < H2; base += 1024) {
        int i = base + t * 4;
        float4 w = *(const float4*)(row + i);
        const float* __restrict__ src = (i < H) ? (e + i) : (hidden + (i - H));
        float4 v = *(const float4*)src;
        acc += w.x * v.x + w.y * v.y + w.z * v.z + w.w * v.w;
    }
    acc = wave_reduce_sum(acc);
    __shared__ float sh[4];
    if ((t & 63) == 0) sh[t >> 6] = acc;
    __syncthreads();
    if (t == 0) ws[WS_ATT + l] = sh[0] + sh[1] + sh[2] + sh[3] + attn_b[l];
}

// K2: softmax over L=100; writes weights to ws and d_out[V+H ..]
// grid 1 x 128
__global__ void k_attn_softmax(float* __restrict__ ws, float* __restrict__ out) {
    const int t = threadIdx.x;  // 128
    __shared__ float sh[128];
    float v = (t < L) ? ws[WS_ATT + t] : -INFINITY;
    sh[t] = v;
    __syncthreads();
    for (int s = 64; s > 0; s >>= 1) {
        if (t < s) sh[t] = fmaxf(sh[t], sh[t + s]);
        __syncthreads();
    }
    float m = sh[0];
    __syncthreads();
    float e = (t < L) ? expf(v - m) : 0.f;
    sh[t] = e;
    __syncthreads();
    for (int s = 64; s > 0; s >>= 1) {
        if (t < s) sh[t] += sh[t + s];
        __syncthreads();
    }
    float denom = sh[0];
    if (t < L) {
        float w = e / denom;
        ws[WS_ATT + t] = w;
        out[V + H + t] = w;
    }
}

// K3: context[h] = sum_l w[l]*enc[l,h]   grid 8 x 128
__global__ void k_context(const float* __restrict__ enc, float* __restrict__ ws) {
    const int h = blockIdx.x * 128 + threadIdx.x;
    float acc = 0.f;
#pragma unroll 4
    for (int l = 0; l < L; ++l) acc += ws[WS_ATT + l] * enc[(size_t)l * H + h];
    ws[WS_CTX + h] = acc;
}

// K4: x[j] = relu(dot(concat(embedded,context), comb_W[j]) + comb_b[j])
// grid 256 x 256 (wave per row)
__global__ void k_combine(const int* __restrict__ tok,
                          const float* __restrict__ emb,
                          const float* __restrict__ comb_W,
                          const float* __restrict__ comb_b,
                          float* __restrict__ ws) {
    const int t = threadIdx.x;
    const int wave = t >> 6, lane = t & 63;
    const int j = blockIdx.x * 4 + wave;
    const float* __restrict__ e   = emb + (size_t)tok[0] * H;
    const float* __restrict__ ctx = ws + WS_CTX;
    const float* __restrict__ row = comb_W + (size_t)j * H2;
    float acc = 0.f;
#pragma unroll
    for (int it = 0; it < 8; ++it) {
        int i = it * 256 + lane * 4;
        float4 w = *(const float4*)(row + i);
        const float* __restrict__ src = (i < H) ? (e + i) : (ctx + (i - H));
        float4 v = *(const float4*)src;
        acc += w.x * v.x + w.y * v.y + w.z * v.z + w.w * v.w;
    }
    acc = wave_reduce_sum(acc);
    if (lane == 0) ws[WS_X + j] = fmaxf(acc + comb_b[j], 0.f);
}

// K5: GRU step, one block per output element j; 6 waves = 6 dot products
// grid 1024 x 384
__global__ void k_gru(const float* __restrict__ hidden,
                      const float* __restrict__ W_ih,
                      const float* __restrict__ W_hh,
                      const float* __restrict__ b_ih,
                      const float* __restrict__ b_hh,
                      float* __restrict__ ws,
                      float* __restrict__ out) {
    const int j = blockIdx.x;
    const int t = threadIdx.x;  // 384
    const int w = t >> 6, lane = t & 63;
    const float* __restrict__ vec = (w < 3) ? (ws + WS_X) : hidden;
    const float* __restrict__ row = (w < 3)
        ? (W_ih + ((size_t)w * H + j) * H)
        : (W_hh + ((size_t)(w - 3) * H + j) * H);
    float acc = 0.f;
#pragma unroll
    for (int it = 0; it < 4; ++it) {
        int i = it * 256 + lane * 4;
        float4 a = *(const float4*)(row + i);
        float4 v = *(const float4*)(vec + i);
        acc += a.x * v.x + a.y * v.y + a.z * v.z + a.w * v.w;
    }
    acc = wave_reduce_sum(acc);
    __shared__ float sh[6];
    if (lane == 0) sh[w] = acc;
    __syncthreads();
    if (t == 0) {
        float ir  = sh[0] + b_ih[j];
        float iz  = sh[1] + b_ih[H + j];
        float inn = sh[2] + b_ih[2 * H + j];
        float hr  = sh[3] + b_hh[j];
        float hz  = sh[4] + b_hh[H + j];
        float hn  = sh[5] + b_hh[2 * H + j];
        float r = 1.f / (1.f + expf(-(ir + hr)));
        float z = 1.f / (1.f + expf(-(iz + hz)));
        float n = tanhf(inn + r * hn);
        float hnew = (1.f - z) * n + z * hidden[j];
        out[V + j]       = hnew;  // output slot (unaligned for float4 -> mirror)
        ws[WS_HNEW + j]  = hnew;  // aligned mirror for the GEMV
    }
}

// K6: logits[v] = dot(out_W[v], h_new) + out_b[v]  -> d_out[v]
// grid ceil(V/4) x 256 (wave per row), h_new staged in LDS
__global__ void k_out_gemv(const float* __restrict__ out_W,
                           const float* __restrict__ out_b,
                           const float* __restrict__ ws,
                           float* __restrict__ out) {
    __shared__ float sh[H];
    const int t = threadIdx.x;
    *(float4*)(sh + t * 4) = *(const float4*)(ws + WS_HNEW + t * 4);
    __syncthreads();
    const int wave = t >> 6, lane = t & 63;
    const int v = blockIdx.x * 4 + wave;
    if (v >= V) return;
    const float* __restrict__ row = out_W + (size_t)v * H;
    float acc = 0.f;
#pragma unroll
    for (int it = 0; it < 4; ++it) {
        int i = it * 256 + lane * 4;
        float4 a = *(const float4*)(row + i);
        float4 b = *(const float4*)(sh + i);
        acc += a.x * b.x + a.y * b.y + a.z * b.z + a.w * b.w;
    }
    acc = wave_reduce_sum(acc);
    if (lane == 0) out[v] = acc + out_b[v];
}

// K7: c = max + log(sum exp(logit - max)), online, single block
// grid 1 x 1024
__global__ void k_lse(const float* __restrict__ out, float* __restrict__ ws) {
    const int t = threadIdx.x;  // 1024
    float m = -INFINITY, s = 0.f;
    const int V4 = V & ~3;  // 50256
    for (int v = t * 4; v < V4; v += 4096) {
        float4 x = *(const float4*)(out + v);
        float lm = fmaxf(fmaxf(x.x, x.y), fmaxf(x.z, x.w));
        float ls = expf(x.x - lm) + expf(x.y - lm) + expf(x.z - lm) + expf(x.w - lm);
        if (lm > m) { s = s * expf(m - lm) + ls; m = lm; }
        else        { s += ls * expf(lm - m); }
    }
    for (int v = V4 + t; v < V; v += 1024) {
        float x = out[v];
        if (x > m) { s = s * expf(m - x) + 1.f; m = x; }
        else       { s += expf(x - m); }
    }
#pragma unroll
    for (int off = 32; off > 0; off >>= 1) {
        float m2 = __shfl_down(m, off);
        float s2 = __shfl_down(s, off);
        float M = fmaxf(m, m2);
        s = s * expf(m - M) + s2 * expf(m2 - M);
        m = M;
    }
    __shared__ float shm[16], shs[16];
    const int wave = t >> 6, lane = t & 63;
    if (lane == 0) { shm[wave] = m; shs[wave] = s; }
    __syncthreads();
    if (t == 0) {
        float M = shm[0], S = shs[0];
        for (int i = 1; i < 16; ++i) {
            float M2 = fmaxf(M, shm[i]);
            S = S * expf(M - M2) + shs[i] * expf(shm[i] - M2);
            M = M2;
        }
        ws[WS_C] = M + logf(S);
    }
}

// K8: out[v] -= c   grid ceil(V/256) x 256
__global__ void k_sub(float* __restrict__ out, const float* __restrict__ ws) {
    const int v = blockIdx.x * 256 + threadIdx.x;
    if (v < V) out[v] -= ws[WS_C];
}

extern "C" void kernel_launch(void* const* d_in, const int* in_sizes, int n_in,
                              void* d_out, int out_size, void* d_ws, size_t ws_size,
                              hipStream_t stream) {
    const int*   tok    = (const int*)d_in[0];
    const float* hidden = (const float*)d_in[1];
    const float* enc    = (const float*)d_in[2];
    const float* emb    = (const float*)d_in[3];
    const float* attn_W = (const float*)d_in[4];
    const float* attn_b = (const float*)d_in[5];
    const float* comb_W = (const float*)d_in[6];
    const float* comb_b = (const float*)d_in[7];
    const float* W_ih   = (const float*)d_in[8];
    const float* W_hh   = (const float*)d_in[9];
    const float* b_ih   = (const float*)d_in[10];
    const float* b_hh   = (const float*)d_in[11];
    const float* out_W  = (const float*)d_in[12];
    const float* out_b  = (const float*)d_in[13];
    float* out = (float*)d_out;
    float* ws  = (float*)d_ws;

    k_attn_logits<<<L, 256, 0, stream>>>(tok, hidden, emb, attn_W, attn_b, ws);
    k_attn_softmax<<<1, 128, 0, stream>>>(ws, out);
    k_context<<<8, 128, 0, stream>>>(enc, ws);
    k_combine<<<256, 256, 0, stream>>>(tok, emb, comb_W, comb_b, ws);
    k_gru<<<H, 384, 0, stream>>>(hidden, W_ih, W_hh, b_ih, b_hh, ws, out);
    k_out_gemv<<<(V + 3) / 4, 256, 0, stream>>>(out_W, out_b, ws, out);
    k_lse<<<1, 1024, 0, stream>>>(out, ws);
    k_sub<<<(V + 255) / 256, 256, 0, stream>>>(out, ws);
}

// Round 3
// 420.246 us; speedup vs baseline: 1.0344x; 1.0344x over previous
//
#include <hip/hip_runtime.h>
#include <math.h>

#define H   1024
#define H2  2048
#define L   100
#define V   50257

#define ROWS_PB 16
#define NBLK_OUT ((V + ROWS_PB - 1) / ROWS_PB)   // 3142

// ws float offsets (16B aligned)
#define WS_ATT   0      // 100 floats: attn logits
#define WS_CTX   128    // 1024 floats: context
#define WS_X     1280   // 1024 floats: relu(combine)
#define WS_HNEW  2304   // 1024 floats: h_new aligned mirror
#define WS_PART  3328   // 2*NBLK_OUT floats: per-block (max, sumexp)
#define WS_C     9728   // 1 float: logsumexp

typedef float floatx4 __attribute__((ext_vector_type(4)));

__device__ __forceinline__ float wave_reduce_sum(float v) {
#pragma unroll
    for (int off = 32; off > 0; off >>= 1) v += __shfl_down(v, off);
    return v;
}

// K1: attn_logits[l] = dot(concat(embedded,h0), attn_W[l]) + attn_b[l]
__global__ void k_attn_logits(const int* __restrict__ tok,
                              const float* __restrict__ hidden,
                              const float* __restrict__ emb,
                              const float* __restrict__ attn_W,
                              const float* __restrict__ attn_b,
                              float* __restrict__ ws) {
    const int l = blockIdx.x;
    const int t = threadIdx.x;  // 256
    const float* __restrict__ row = attn_W + (size_t)l * H2;
    const float* __restrict__ e   = emb + (size_t)tok[0] * H;
    float acc = 0.f;
#pragma unroll
    for (int base = 0; base < H2; base += 1024) {
        int i = base + t * 4;
        float4 w = *(const float4*)(row + i);
        const float* __restrict__ src = (i < H) ? (e + i) : (hidden + (i - H));
        float4 v = *(const float4*)src;
        acc += w.x * v.x + w.y * v.y + w.z * v.z + w.w * v.w;
    }
    acc = wave_reduce_sum(acc);
    __shared__ float sh[4];
    if ((t & 63) == 0) sh[t >> 6] = acc;
    __syncthreads();
    if (t == 0) ws[WS_ATT + l] = sh[0] + sh[1] + sh[2] + sh[3] + attn_b[l];
}

// K2: fused softmax(100) + context slice. grid 8 x 128.
__global__ void k_ctx(const float* __restrict__ enc,
                      float* __restrict__ ws,
                      float* __restrict__ out) {
    const int t = threadIdx.x;  // 128
    __shared__ float sl[128];
    __shared__ float shw[L];
    float v = (t < L) ? ws[WS_ATT + t] : -INFINITY;
    sl[t] = v;
    __syncthreads();
    for (int s = 64; s > 0; s >>= 1) {
        if (t < s) sl[t] = fmaxf(sl[t], sl[t + s]);
        __syncthreads();
    }
    float m = sl[0];
    __syncthreads();
    float e = (t < L) ? expf(v - m) : 0.f;
    sl[t] = e;
    __syncthreads();
    for (int s = 64; s > 0; s >>= 1) {
        if (t < s) sl[t] += sl[t + s];
        __syncthreads();
    }
    float denom = sl[0];
    if (t < L) {
        float w = e / denom;
        shw[t] = w;
        if (blockIdx.x == 0) out[V + H + t] = w;   // attn_weights output
    }
    __syncthreads();
    const int h = blockIdx.x * 128 + t;
    float acc = 0.f;
#pragma unroll 4
    for (int l = 0; l < L; ++l) acc += shw[l] * enc[(size_t)l * H + h];
    ws[WS_CTX + h] = acc;
}

// K3: x[j] = relu(dot(concat(embedded,context), comb_W[j]) + comb_b[j])
__global__ void k_combine(const int* __restrict__ tok,
                          const float* __restrict__ emb,
                          const float* __restrict__ comb_W,
                          const float* __restrict__ comb_b,
                          float* __restrict__ ws) {
    const int t = threadIdx.x;
    const int wave = t >> 6, lane = t & 63;
    const int j = blockIdx.x * 4 + wave;
    const float* __restrict__ e   = emb + (size_t)tok[0] * H;
    const float* __restrict__ ctx = ws + WS_CTX;
    const float* __restrict__ row = comb_W + (size_t)j * H2;
    float acc = 0.f;
#pragma unroll
    for (int it = 0; it < 8; ++it) {
        int i = it * 256 + lane * 4;
        float4 w = *(const float4*)(row + i);
        const float* __restrict__ src = (i < H) ? (e + i) : (ctx + (i - H));
        float4 v = *(const float4*)src;
        acc += w.x * v.x + w.y * v.y + w.z * v.z + w.w * v.w;
    }
    acc = wave_reduce_sum(acc);
    if (lane == 0) ws[WS_X + j] = fmaxf(acc + comb_b[j], 0.f);
}

// K4: GRU step, block per j; 6 waves = 6 dot products
__global__ void k_gru(const float* __restrict__ hidden,
                      const float* __restrict__ W_ih,
                      const float* __restrict__ W_hh,
                      const float* __restrict__ b_ih,
                      const float* __restrict__ b_hh,
                      float* __restrict__ ws,
                      float* __restrict__ out) {
    const int j = blockIdx.x;
    const int t = threadIdx.x;  // 384
    const int w = t >> 6, lane = t & 63;
    const float* __restrict__ vec = (w < 3) ? (ws + WS_X) : hidden;
    const float* __restrict__ row = (w < 3)
        ? (W_ih + ((size_t)w * H + j) * H)
        : (W_hh + ((size_t)(w - 3) * H + j) * H);
    float acc = 0.f;
#pragma unroll
    for (int it = 0; it < 4; ++it) {
        int i = it * 256 + lane * 4;
        float4 a = *(const float4*)(row + i);
        float4 v = *(const float4*)(vec + i);
        acc += a.x * v.x + a.y * v.y + a.z * v.z + a.w * v.w;
    }
    acc = wave_reduce_sum(acc);
    __shared__ float sh[6];
    if (lane == 0) sh[w] = acc;
    __syncthreads();
    if (t == 0) {
        float ir  = sh[0] + b_ih[j];
        float iz  = sh[1] + b_ih[H + j];
        float inn = sh[2] + b_ih[2 * H + j];
        float hr  = sh[3] + b_hh[j];
        float hz  = sh[4] + b_hh[H + j];
        float hn  = sh[5] + b_hh[2 * H + j];
        float r = 1.f / (1.f + expf(-(ir + hr)));
        float z = 1.f / (1.f + expf(-(iz + hz)));
        float n = tanhf(inn + r * hn);
        float hnew = (1.f - z) * n + z * hidden[j];
        out[V + j]      = hnew;
        ws[WS_HNEW + j] = hnew;
    }
}

// K5: big GEMV. 16 rows/block, 4 rows/wave interleaved for MLP.
// Nontemporal loads on the 206 MB stream. Fused per-block partial (m, sumexp).
__global__ void k_out_gemv(const float* __restrict__ out_W,
                           const float* __restrict__ out_b,
                           const float* __restrict__ ws,
                           float* __restrict__ out,
                           float* __restrict__ part) {
    __shared__ float shv[H];
    __shared__ float slog[ROWS_PB];
    const int t = threadIdx.x;  // 256
    *(float4*)(shv + t * 4) = *(const float4*)(ws + WS_HNEW + t * 4);
    __syncthreads();
    const int wave = t >> 6, lane = t & 63;
    const int r0 = blockIdx.x * ROWS_PB + wave * 4;
    const float* __restrict__ base = out_W + (size_t)r0 * H;
    float acc0 = 0.f, acc1 = 0.f, acc2 = 0.f, acc3 = 0.f;
    if (r0 + 3 < V) {
#pragma unroll
        for (int it = 0; it < 4; ++it) {
            const int i = it * 256 + lane * 4;
            float4 b = *(const float4*)(shv + i);
            floatx4 a0 = __builtin_nontemporal_load((const floatx4*)(base + i));
            floatx4 a1 = __builtin_nontemporal_load((const floatx4*)(base + H + i));
            floatx4 a2 = __builtin_nontemporal_load((const floatx4*)(base + 2 * H + i));
            floatx4 a3 = __builtin_nontemporal_load((const floatx4*)(base + 3 * H + i));
            acc0 += a0.x * b.x + a0.y * b.y + a0.z * b.z + a0.w * b.w;
            acc1 += a1.x * b.x + a1.y * b.y + a1.z * b.z + a1.w * b.w;
            acc2 += a2.x * b.x + a2.y * b.y + a2.z * b.z + a2.w * b.w;
            acc3 += a3.x * b.x + a3.y * b.y + a3.z * b.z + a3.w * b.w;
        }
    } else {
        for (int it = 0; it < 4; ++it) {
            const int i = it * 256 + lane * 4;
            float4 b = *(const float4*)(shv + i);
            if (r0 + 0 < V) { float4 a = *(const float4*)(base + i);
                acc0 += a.x * b.x + a.y * b.y + a.z * b.z + a.w * b.w; }
            if (r0 + 1 < V) { float4 a = *(const float4*)(base + H + i);
                acc1 += a.x * b.x + a.y * b.y + a.z * b.z + a.w * b.w; }
            if (r0 + 2 < V) { float4 a = *(const float4*)(base + 2 * H + i);
                acc2 += a.x * b.x + a.y * b.y + a.z * b.z + a.w * b.w; }
            if (r0 + 3 < V) { float4 a = *(const float4*)(base + 3 * H + i);
                acc3 += a.x * b.x + a.y * b.y + a.z * b.z + a.w * b.w; }
        }
    }
    acc0 = wave_reduce_sum(acc0);
    acc1 = wave_reduce_sum(acc1);
    acc2 = wave_reduce_sum(acc2);
    acc3 = wave_reduce_sum(acc3);
    if (lane == 0) {
        float lg[4] = {acc0, acc1, acc2, acc3};
#pragma unroll
        for (int r = 0; r < 4; ++r) {
            int row = r0 + r;
            float l = (row < V) ? lg[r] + out_b[row] : -INFINITY;
            if (row < V) out[row] = l;
            slog[wave * 4 + r] = l;
        }
    }
    __syncthreads();
    if (t == 0) {
        float m = slog[0];
#pragma unroll
        for (int i = 1; i < ROWS_PB; ++i) m = fmaxf(m, slog[i]);
        float s = 0.f;
#pragma unroll
        for (int i = 0; i < ROWS_PB; ++i) s += expf(slog[i] - m);
        part[2 * blockIdx.x]     = m;
        part[2 * blockIdx.x + 1] = s;
    }
}

// K6: reduce NBLK_OUT (m,s) pairs -> c = M + log(S). 1 block x 256.
__global__ void k_lse(const float* __restrict__ part, float* __restrict__ ws) {
    const int t = threadIdx.x;  // 256
    float m = -INFINITY, s = 0.f;
    for (int i = t; i < NBLK_OUT; i += 256) {
        float pm = part[2 * i], ps = part[2 * i + 1];
        if (pm > m) { s = s * expf(m - pm) + ps; m = pm; }
        else        { s += ps * expf(pm - m); }
    }
#pragma unroll
    for (int off = 32; off > 0; off >>= 1) {
        float m2 = __shfl_down(m, off);
        float s2 = __shfl_down(s, off);
        float M = fmaxf(m, m2);
        s = s * expf(m - M) + s2 * expf(m2 - M);
        m = M;
    }
    __shared__ float shm[4], shs[4];
    const int wave = t >> 6, lane = t & 63;
    if (lane == 0) { shm[wave] = m; shs[wave] = s; }
    __syncthreads();
    if (t == 0) {
        float M = shm[0], S = shs[0];
        for (int i = 1; i < 4; ++i) {
            float M2 = fmaxf(M, shm[i]);
            S = S * expf(M - M2) + shs[i] * expf(shm[i] - M2);
            M = M2;
        }
        ws[WS_C] = M + logf(S);
    }
}

// K7: out[v] -= c
__global__ void k_sub(float* __restrict__ out, const float* __restrict__ ws) {
    const int v = blockIdx.x * 256 + threadIdx.x;
    if (v < V) out[v] -= ws[WS_C];
}

extern "C" void kernel_launch(void* const* d_in, const int* in_sizes, int n_in,
                              void* d_out, int out_size, void* d_ws, size_t ws_size,
                              hipStream_t stream) {
    const int*   tok    = (const int*)d_in[0];
    const float* hidden = (const float*)d_in[1];
    const float* enc    = (const float*)d_in[2];
    const float* emb    = (const float*)d_in[3];
    const float* attn_W = (const float*)d_in[4];
    const float* attn_b = (const float*)d_in[5];
    const float* comb_W = (const float*)d_in[6];
    const float* comb_b = (const float*)d_in[7];
    const float* W_ih   = (const float*)d_in[8];
    const float* W_hh   = (const float*)d_in[9];
    const float* b_ih   = (const float*)d_in[10];
    const float* b_hh   = (const float*)d_in[11];
    const float* out_W  = (const float*)d_in[12];
    const float* out_b  = (const float*)d_in[13];
    float* out = (float*)d_out;
    float* ws  = (float*)d_ws;

    k_attn_logits<<<L, 256, 0, stream>>>(tok, hidden, emb, attn_W, attn_b, ws);
    k_ctx<<<8, 128, 0, stream>>>(enc, ws, out);
    k_combine<<<256, 256, 0, stream>>>(tok, emb, comb_W, comb_b, ws);
    k_gru<<<H, 384, 0, stream>>>(hidden, W_ih, W_hh, b_ih, b_hh, ws, out);
    k_out_gemv<<<NBLK_OUT, 256, 0, stream>>>(out_W, out_b, ws, out, ws + WS_PART);
    k_lse<<<1, 256, 0, stream>>>(ws + WS_PART, ws);
    k_sub<<<(V + 255) / 256, 256, 0, stream>>>(out, ws);
}